// Round 1
// baseline (1068.009 us; speedup 1.0000x reference)
//
#include <hip/hip_runtime.h>
#include <math.h>

#define N_NODES 100000
#define EMB 128
#define N_EDGES 1600000
#define N_LAYERS 3
#define SCAN_BLK 256
#define N_SCAN_BLOCKS ((N_NODES + SCAN_BLK - 1) / SCAN_BLK)  // 391

// ---------------- CSR build ----------------

__global__ __launch_bounds__(256) void hist_kernel(const int* __restrict__ dst,
                                                   int* __restrict__ counts) {
  int i = blockIdx.x * 256 + threadIdx.x;
  if (i < N_EDGES) atomicAdd(&counts[dst[i]], 1);
}

__global__ __launch_bounds__(256) void scan1_kernel(const int* __restrict__ counts,
                                                    int* __restrict__ partials) {
  __shared__ int sdata[256];
  int t = threadIdx.x;
  int idx = blockIdx.x * 256 + t;
  sdata[t] = (idx < N_NODES) ? counts[idx] : 0;
  __syncthreads();
  for (int off = 128; off > 0; off >>= 1) {
    if (t < off) sdata[t] += sdata[t + off];
    __syncthreads();
  }
  if (t == 0) partials[blockIdx.x] = sdata[0];
}

__global__ __launch_bounds__(512) void scan2_kernel(int* __restrict__ partials) {
  __shared__ int s[512];
  int t = threadIdx.x;
  int v = (t < N_SCAN_BLOCKS) ? partials[t] : 0;
  s[t] = v;
  __syncthreads();
  for (int off = 1; off < 512; off <<= 1) {
    int tmp = (t >= off) ? s[t - off] : 0;
    __syncthreads();
    s[t] += tmp;
    __syncthreads();
  }
  if (t < N_SCAN_BLOCKS) partials[t] = s[t] - v;  // exclusive prefix of block sums
}

__global__ __launch_bounds__(256) void scan3_kernel(const int* __restrict__ counts,
                                                    const int* __restrict__ partials,
                                                    int* __restrict__ row_ptr,
                                                    int* __restrict__ cursor) {
  __shared__ int s[256];
  int t = threadIdx.x;
  int b = blockIdx.x;
  int idx = b * 256 + t;
  int v = (idx < N_NODES) ? counts[idx] : 0;
  s[t] = v;
  __syncthreads();
  for (int off = 1; off < 256; off <<= 1) {
    int tmp = (t >= off) ? s[t - off] : 0;
    __syncthreads();
    s[t] += tmp;
    __syncthreads();
  }
  if (idx < N_NODES) {
    int val = s[t] - v + partials[b];
    row_ptr[idx] = val;
    cursor[idx] = val;
  }
  if (b == 0 && t == 0) row_ptr[N_NODES] = N_EDGES;
}

__global__ __launch_bounds__(256) void fill_kernel(const int* __restrict__ src,
                                                   const int* __restrict__ dst,
                                                   int* __restrict__ cursor,
                                                   int* __restrict__ col) {
  int i = blockIdx.x * 256 + threadIdx.x;
  if (i < N_EDGES) {
    int d = dst[i];
    int p = atomicAdd(&cursor[d], 1);
    col[p] = src[i];
  }
}

// ---------------- per-layer compute ----------------

// one wave per node: m[v] = deg_inv[v] * sum_{u in N(v)} x[u]
__global__ __launch_bounds__(256) void aggregate_kernel(const float* __restrict__ x,
                                                        const int* __restrict__ row_ptr,
                                                        const int* __restrict__ col,
                                                        const float* __restrict__ deg_inv,
                                                        float* __restrict__ m) {
  int gw = (blockIdx.x * 256 + threadIdx.x) >> 6;
  int lane = threadIdx.x & 63;
  int v = __builtin_amdgcn_readfirstlane(gw);  // wave-uniform node id -> SGPR
  if (v >= N_NODES) return;
  int beg = row_ptr[v];
  int end = row_ptr[v + 1];
  float accx = 0.f, accy = 0.f;
  const float* xl = x + (size_t)lane * 2;
  for (int e = beg; e < end; ++e) {
    int u = col[e];  // wave-uniform -> scalar load
    float2 t = *(const float2*)(xl + (size_t)u * EMB);
    accx += t.x;
    accy += t.y;
  }
  float di = deg_inv[v];
  *(float2*)(m + (size_t)v * EMB + lane * 2) = make_float2(accx * di, accy * di);
}

__device__ __forceinline__ float gelu_exact(float v) {
  return 0.5f * v * (1.f + erff(v * 0.70710678118654752f));
}

// x[row] += gelu(m[row] @ W + bias); W staged in LDS; one wave per row.
__global__ __launch_bounds__(256) void gemm_kernel(const float* __restrict__ m,
                                                   const float* __restrict__ W,
                                                   const float* __restrict__ bias,
                                                   float* __restrict__ x) {
  __shared__ float sW[EMB * EMB];
  for (int i = threadIdx.x; i < EMB * EMB / 4; i += 256)
    ((float4*)sW)[i] = ((const float4*)W)[i];
  __syncthreads();

  int lane = threadIdx.x & 63;
  int j = lane * 2;
  int gw = (blockIdx.x * 256 + threadIdx.x) >> 6;
  int nw = gridDim.x * 4;
  float2 bj = *(const float2*)(bias + j);

  for (int row = gw; row < N_NODES; row += nw) {
    int r = __builtin_amdgcn_readfirstlane(row);  // wave-uniform row -> scalar m loads
    const float* mrow = m + (size_t)r * EMB;
    float acc0 = 0.f, acc1 = 0.f;
#pragma unroll 16
    for (int k = 0; k < EMB; ++k) {
      float mk = mrow[k];
      float2 w = *(const float2*)(&sW[k * EMB + j]);
      acc0 = fmaf(mk, w.x, acc0);
      acc1 = fmaf(mk, w.y, acc1);
    }
    float h0 = gelu_exact(acc0 + bj.x);
    float h1 = gelu_exact(acc1 + bj.y);
    float* xp = x + (size_t)r * EMB + j;
    float2 xr = *(float2*)xp;
    xr.x += h0;
    xr.y += h1;
    *(float2*)xp = xr;
  }
}

// in-place LayerNorm over feature dim; one wave per row
__global__ __launch_bounds__(256) void ln_kernel(float* __restrict__ x,
                                                 const float* __restrict__ gamma,
                                                 const float* __restrict__ beta) {
  int gw = (blockIdx.x * 256 + threadIdx.x) >> 6;
  int lane = threadIdx.x & 63;
  if (gw >= N_NODES) return;
  float* xp = x + (size_t)gw * EMB + lane * 2;
  float2 v = *(const float2*)xp;
  float s = v.x + v.y;
  float sq = fmaf(v.x, v.x, v.y * v.y);
  for (int off = 1; off < 64; off <<= 1) {
    s += __shfl_xor(s, off, 64);
    sq += __shfl_xor(sq, off, 64);
  }
  float mu = s * (1.f / EMB);
  float var = sq * (1.f / EMB) - mu * mu;
  float rstd = rsqrtf(var + 1e-5f);
  float2 g = *(const float2*)(gamma + lane * 2);
  float2 be = *(const float2*)(beta + lane * 2);
  float2 o;
  o.x = (v.x - mu) * rstd * g.x + be.x;
  o.y = (v.y - mu) * rstd * g.y + be.y;
  *(float2*)xp = o;
}

// ---------------- launch ----------------

extern "C" void kernel_launch(void* const* d_in, const int* in_sizes, int n_in,
                              void* d_out, int out_size, void* d_ws, size_t ws_size,
                              hipStream_t stream) {
  const int* edge_index = (const int*)d_in[0];
  const float* deg_inv = (const float*)d_in[1];
  const float* node_emb = (const float*)d_in[2];
  const float* W = (const float*)d_in[3];
  const float* b = (const float*)d_in[4];
  const float* gamma = (const float*)d_in[5];
  const float* beta = (const float*)d_in[6];
  const int* src = edge_index;
  const int* dst = edge_index + N_EDGES;
  float* x = (float*)d_out;  // x lives in d_out; LN finalizes in place

  // workspace layout (all offsets padded to 256B)
  char* ws = (char*)d_ws;
  auto take = [&](size_t bytes) {
    char* p = ws;
    ws += (bytes + 255) & ~(size_t)255;
    return p;
  };
  float* m = (float*)take((size_t)N_NODES * EMB * sizeof(float));
  int* counts = (int*)take(N_NODES * sizeof(int));
  int* row_ptr = (int*)take((N_NODES + 1) * sizeof(int));
  int* cursor = (int*)take(N_NODES * sizeof(int));
  int* col = (int*)take(N_EDGES * sizeof(int));
  int* partials = (int*)take(512 * sizeof(int));

  hipMemcpyAsync(x, node_emb, (size_t)N_NODES * EMB * sizeof(float),
                 hipMemcpyDeviceToDevice, stream);
  hipMemsetAsync(counts, 0, N_NODES * sizeof(int), stream);

  hist_kernel<<<(N_EDGES + 255) / 256, 256, 0, stream>>>(dst, counts);
  scan1_kernel<<<N_SCAN_BLOCKS, 256, 0, stream>>>(counts, partials);
  scan2_kernel<<<1, 512, 0, stream>>>(partials);
  scan3_kernel<<<N_SCAN_BLOCKS, 256, 0, stream>>>(counts, partials, row_ptr, cursor);
  fill_kernel<<<(N_EDGES + 255) / 256, 256, 0, stream>>>(src, dst, cursor, col);

  for (int l = 0; l < N_LAYERS; ++l) {
    aggregate_kernel<<<(N_NODES + 3) / 4, 256, 0, stream>>>(x, row_ptr, col, deg_inv, m);
    gemm_kernel<<<1024, 256, 0, stream>>>(m, W + (size_t)l * EMB * EMB,
                                          b + (size_t)l * EMB, x);
  }
  ln_kernel<<<(N_NODES + 3) / 4, 256, 0, stream>>>(x, gamma, beta);
}

// Round 2
// 805.968 us; speedup vs baseline: 1.3251x; 1.3251x over previous
//
#include <hip/hip_runtime.h>
#include <math.h>

#define N_NODES 100000
#define EMB 128
#define N_EDGES 1600000
#define N_LAYERS 3
#define SCAN_BLK 256
#define N_SCAN_BLOCKS ((N_NODES + SCAN_BLK - 1) / SCAN_BLK)  // 391
#define BM 32                 // m-rows per block tile (100000 % 32 == 0)
#define GEMM_BLOCKS 512       // 2 blocks/CU persistent

// ---------------- CSR build ----------------

__global__ __launch_bounds__(256) void hist_kernel(const int* __restrict__ dst,
                                                   int* __restrict__ counts) {
  int i = blockIdx.x * 256 + threadIdx.x;
  if (i < N_EDGES) atomicAdd(&counts[dst[i]], 1);
}

__global__ __launch_bounds__(256) void scan1_kernel(const int* __restrict__ counts,
                                                    int* __restrict__ partials) {
  __shared__ int sdata[256];
  int t = threadIdx.x;
  int idx = blockIdx.x * 256 + t;
  sdata[t] = (idx < N_NODES) ? counts[idx] : 0;
  __syncthreads();
  for (int off = 128; off > 0; off >>= 1) {
    if (t < off) sdata[t] += sdata[t + off];
    __syncthreads();
  }
  if (t == 0) partials[blockIdx.x] = sdata[0];
}

__global__ __launch_bounds__(512) void scan2_kernel(int* __restrict__ partials) {
  __shared__ int s[512];
  int t = threadIdx.x;
  int v = (t < N_SCAN_BLOCKS) ? partials[t] : 0;
  s[t] = v;
  __syncthreads();
  for (int off = 1; off < 512; off <<= 1) {
    int tmp = (t >= off) ? s[t - off] : 0;
    __syncthreads();
    s[t] += tmp;
    __syncthreads();
  }
  if (t < N_SCAN_BLOCKS) partials[t] = s[t] - v;  // exclusive prefix of block sums
}

__global__ __launch_bounds__(256) void scan3_kernel(const int* __restrict__ counts,
                                                    const int* __restrict__ partials,
                                                    int* __restrict__ row_ptr,
                                                    int* __restrict__ cursor) {
  __shared__ int s[256];
  int t = threadIdx.x;
  int b = blockIdx.x;
  int idx = b * 256 + t;
  int v = (idx < N_NODES) ? counts[idx] : 0;
  s[t] = v;
  __syncthreads();
  for (int off = 1; off < 256; off <<= 1) {
    int tmp = (t >= off) ? s[t - off] : 0;
    __syncthreads();
    s[t] += tmp;
    __syncthreads();
  }
  if (idx < N_NODES) {
    int val = s[t] - v + partials[b];
    row_ptr[idx] = val;
    cursor[idx] = val;
  }
  if (b == 0 && t == 0) row_ptr[N_NODES] = N_EDGES;
}

__global__ __launch_bounds__(256) void fill_kernel(const int* __restrict__ src,
                                                   const int* __restrict__ dst,
                                                   int* __restrict__ cursor,
                                                   int* __restrict__ col) {
  int i = blockIdx.x * 256 + threadIdx.x;
  if (i < N_EDGES) {
    int d = dst[i];
    int p = atomicAdd(&cursor[d], 1);
    col[p] = src[i];
  }
}

// ---------------- per-layer compute ----------------

// one wave per node: m[v] = deg_inv[v] * sum_{u in N(v)} x[u]
__global__ __launch_bounds__(256) void aggregate_kernel(const float* __restrict__ x,
                                                        const int* __restrict__ row_ptr,
                                                        const int* __restrict__ col,
                                                        const float* __restrict__ deg_inv,
                                                        float* __restrict__ m) {
  int gw = (blockIdx.x * 256 + threadIdx.x) >> 6;
  int lane = threadIdx.x & 63;
  int v = __builtin_amdgcn_readfirstlane(gw);  // wave-uniform node id -> SGPR
  if (v >= N_NODES) return;
  int beg = row_ptr[v];
  int end = row_ptr[v + 1];
  float accx = 0.f, accy = 0.f;
  const float* xl = x + (size_t)lane * 2;
  for (int e = beg; e < end; ++e) {
    int u = col[e];  // wave-uniform -> scalar load
    float2 t = *(const float2*)(xl + (size_t)u * EMB);
    accx += t.x;
    accy += t.y;
  }
  float di = deg_inv[v];
  *(float2*)(m + (size_t)v * EMB + lane * 2) = make_float2(accx * di, accy * di);
}

__device__ __forceinline__ float gelu_exact(float v) {
  return 0.5f * v * (1.f + erff(v * 0.70710678118654752f));
}

// x[row] += gelu(m[row] @ W + bias)
// Persistent blocks; W in LDS (64KB); 32-row m tile in LDS (16KB); 80KB total
// -> exactly 2 blocks/CU. Each of 4 waves computes 8 rows x 128 cols,
// 2 cols/lane, 16 fp32 accumulators.
__global__ __launch_bounds__(256) void gemm_kernel(const float* __restrict__ m,
                                                   const float* __restrict__ W,
                                                   const float* __restrict__ bias,
                                                   float* __restrict__ x) {
  __shared__ float sW[EMB * EMB];       // 64 KB
  __shared__ float sM[BM * EMB];        // 16 KB

  // stage W once per block
  for (int i = threadIdx.x; i < EMB * EMB / 4; i += 256)
    ((float4*)sW)[i] = ((const float4*)W)[i];

  const int wave = threadIdx.x >> 6;    // 0..3
  const int lane = threadIdx.x & 63;
  const int j = lane * 2;               // output col pair
  const float2 bj = *(const float2*)(bias + j);

  // staging map: thread t loads row (t/8), cols (t%8)*16..+15 (4x float4)
  const int str = threadIdx.x >> 3;         // 0..31
  const int stc = (threadIdx.x & 7) * 16;   // col start

  const int NT = N_NODES / BM;  // 3125 tiles, exact
  for (int tile = blockIdx.x; tile < NT; tile += GEMM_BLOCKS) {
    const int row0 = tile * BM;
    __syncthreads();  // prev k-loop reads of sM done (also covers W stage, 1st iter)
    {
      const float4* src = (const float4*)(m + (size_t)(row0 + str) * EMB + stc);
      float4* dstp = (float4*)(sM + str * EMB + stc);
      float4 a0 = src[0], a1 = src[1], a2 = src[2], a3 = src[3];
      dstp[0] = a0; dstp[1] = a1; dstp[2] = a2; dstp[3] = a3;
    }
    __syncthreads();

    const float* mw = sM + wave * 8 * EMB;  // this wave's 8 rows
    float acc[8][2];
#pragma unroll
    for (int r = 0; r < 8; ++r) { acc[r][0] = 0.f; acc[r][1] = 0.f; }

#pragma unroll 4
    for (int k = 0; k < EMB; ++k) {
      float2 w = *(const float2*)(&sW[k * EMB + j]);
      float mk[8];
#pragma unroll
      for (int r = 0; r < 8; ++r) mk[r] = mw[r * EMB + k];  // uniform -> LDS broadcast
#pragma unroll
      for (int r = 0; r < 8; ++r) {
        acc[r][0] = fmaf(mk[r], w.x, acc[r][0]);
        acc[r][1] = fmaf(mk[r], w.y, acc[r][1]);
      }
    }

#pragma unroll
    for (int r = 0; r < 8; ++r) {
      const int row = row0 + wave * 8 + r;
      float* xp = x + (size_t)row * EMB + j;
      float2 xr = *(float2*)xp;
      xr.x += gelu_exact(acc[r][0] + bj.x);
      xr.y += gelu_exact(acc[r][1] + bj.y);
      *(float2*)xp = xr;
    }
  }
}

// in-place LayerNorm over feature dim; one wave per row
__global__ __launch_bounds__(256) void ln_kernel(float* __restrict__ x,
                                                 const float* __restrict__ gamma,
                                                 const float* __restrict__ beta) {
  int gw = (blockIdx.x * 256 + threadIdx.x) >> 6;
  int lane = threadIdx.x & 63;
  if (gw >= N_NODES) return;
  float* xp = x + (size_t)gw * EMB + lane * 2;
  float2 v = *(const float2*)xp;
  float s = v.x + v.y;
  float sq = fmaf(v.x, v.x, v.y * v.y);
  for (int off = 1; off < 64; off <<= 1) {
    s += __shfl_xor(s, off, 64);
    sq += __shfl_xor(sq, off, 64);
  }
  float mu = s * (1.f / EMB);
  float var = sq * (1.f / EMB) - mu * mu;
  float rstd = rsqrtf(var + 1e-5f);
  float2 g = *(const float2*)(gamma + lane * 2);
  float2 be = *(const float2*)(beta + lane * 2);
  float2 o;
  o.x = (v.x - mu) * rstd * g.x + be.x;
  o.y = (v.y - mu) * rstd * g.y + be.y;
  *(float2*)xp = o;
}

// ---------------- launch ----------------

extern "C" void kernel_launch(void* const* d_in, const int* in_sizes, int n_in,
                              void* d_out, int out_size, void* d_ws, size_t ws_size,
                              hipStream_t stream) {
  const int* edge_index = (const int*)d_in[0];
  const float* deg_inv = (const float*)d_in[1];
  const float* node_emb = (const float*)d_in[2];
  const float* W = (const float*)d_in[3];
  const float* b = (const float*)d_in[4];
  const float* gamma = (const float*)d_in[5];
  const float* beta = (const float*)d_in[6];
  const int* src = edge_index;
  const int* dst = edge_index + N_EDGES;
  float* x = (float*)d_out;  // x lives in d_out; LN finalizes in place

  // workspace layout (all offsets padded to 256B)
  char* ws = (char*)d_ws;
  auto take = [&](size_t bytes) {
    char* p = ws;
    ws += (bytes + 255) & ~(size_t)255;
    return p;
  };
  float* m = (float*)take((size_t)N_NODES * EMB * sizeof(float));
  int* counts = (int*)take(N_NODES * sizeof(int));
  int* row_ptr = (int*)take((N_NODES + 1) * sizeof(int));
  int* cursor = (int*)take(N_NODES * sizeof(int));
  int* col = (int*)take(N_EDGES * sizeof(int));
  int* partials = (int*)take(512 * sizeof(int));

  hipMemcpyAsync(x, node_emb, (size_t)N_NODES * EMB * sizeof(float),
                 hipMemcpyDeviceToDevice, stream);
  hipMemsetAsync(counts, 0, N_NODES * sizeof(int), stream);

  hist_kernel<<<(N_EDGES + 255) / 256, 256, 0, stream>>>(dst, counts);
  scan1_kernel<<<N_SCAN_BLOCKS, 256, 0, stream>>>(counts, partials);
  scan2_kernel<<<1, 512, 0, stream>>>(partials);
  scan3_kernel<<<N_SCAN_BLOCKS, 256, 0, stream>>>(counts, partials, row_ptr, cursor);
  fill_kernel<<<(N_EDGES + 255) / 256, 256, 0, stream>>>(src, dst, cursor, col);

  for (int l = 0; l < N_LAYERS; ++l) {
    aggregate_kernel<<<(N_NODES + 3) / 4, 256, 0, stream>>>(x, row_ptr, col, deg_inv, m);
    gemm_kernel<<<GEMM_BLOCKS, 256, 0, stream>>>(m, W + (size_t)l * EMB * EMB,
                                                 b + (size_t)l * EMB, x);
  }
  ln_kernel<<<(N_NODES + 3) / 4, 256, 0, stream>>>(x, gamma, beta);
}

// Round 3
// 689.144 us; speedup vs baseline: 1.5498x; 1.1695x over previous
//
#include <hip/hip_runtime.h>
#include <hip/hip_bf16.h>
#include <math.h>

#define N_NODES 100000
#define EMB 128
#define N_EDGES 1600000
#define N_LAYERS 3
#define SCAN_BLK 256
#define N_SCAN_BLOCKS ((N_NODES + SCAN_BLK - 1) / SCAN_BLK)  // 391

typedef __bf16 bf16x8 __attribute__((ext_vector_type(8)));
typedef float f32x4 __attribute__((ext_vector_type(4)));

// ---------------- CSR build ----------------

__global__ __launch_bounds__(256) void hist_kernel(const int* __restrict__ dst,
                                                   int* __restrict__ counts) {
  int i = blockIdx.x * 256 + threadIdx.x;
  if (i < N_EDGES) atomicAdd(&counts[dst[i]], 1);
}

__global__ __launch_bounds__(256) void scan1_kernel(const int* __restrict__ counts,
                                                    int* __restrict__ partials) {
  __shared__ int sdata[256];
  int t = threadIdx.x;
  int idx = blockIdx.x * 256 + t;
  sdata[t] = (idx < N_NODES) ? counts[idx] : 0;
  __syncthreads();
  for (int off = 128; off > 0; off >>= 1) {
    if (t < off) sdata[t] += sdata[t + off];
    __syncthreads();
  }
  if (t == 0) partials[blockIdx.x] = sdata[0];
}

__global__ __launch_bounds__(512) void scan2_kernel(int* __restrict__ partials) {
  __shared__ int s[512];
  int t = threadIdx.x;
  int v = (t < N_SCAN_BLOCKS) ? partials[t] : 0;
  s[t] = v;
  __syncthreads();
  for (int off = 1; off < 512; off <<= 1) {
    int tmp = (t >= off) ? s[t - off] : 0;
    __syncthreads();
    s[t] += tmp;
    __syncthreads();
  }
  if (t < N_SCAN_BLOCKS) partials[t] = s[t] - v;  // exclusive prefix of block sums
}

__global__ __launch_bounds__(256) void scan3_kernel(const int* __restrict__ counts,
                                                    const int* __restrict__ partials,
                                                    int* __restrict__ row_ptr,
                                                    int* __restrict__ cursor) {
  __shared__ int s[256];
  int t = threadIdx.x;
  int b = blockIdx.x;
  int idx = b * 256 + t;
  int v = (idx < N_NODES) ? counts[idx] : 0;
  s[t] = v;
  __syncthreads();
  for (int off = 1; off < 256; off <<= 1) {
    int tmp = (t >= off) ? s[t - off] : 0;
    __syncthreads();
    s[t] += tmp;
    __syncthreads();
  }
  if (idx < N_NODES) {
    int val = s[t] - v + partials[b];
    row_ptr[idx] = val;
    cursor[idx] = val;
  }
  if (b == 0 && t == 0) row_ptr[N_NODES] = N_EDGES;
}

__global__ __launch_bounds__(256) void fill_kernel(const int* __restrict__ src,
                                                   const int* __restrict__ dst,
                                                   int* __restrict__ cursor,
                                                   int* __restrict__ col) {
  int i = blockIdx.x * 256 + threadIdx.x;
  if (i < N_EDGES) {
    int d = dst[i];
    int p = atomicAdd(&cursor[d], 1);
    col[p] = src[i];
  }
}

// ---------------- precompute ----------------

// xb = bf16(node_emb), 8 elems/thread
__global__ __launch_bounds__(256) void convert_kernel(const float* __restrict__ in,
                                                      __hip_bfloat16* __restrict__ out) {
  size_t i = (size_t)blockIdx.x * 256 + threadIdx.x;  // 1.6M threads exactly
  const float4* p = (const float4*)in + i * 2;
  float4 a = p[0], b = p[1];
  union { __hip_bfloat16 h[8]; uint4 u; } r;
  r.h[0] = __float2bfloat16(a.x); r.h[1] = __float2bfloat16(a.y);
  r.h[2] = __float2bfloat16(a.z); r.h[3] = __float2bfloat16(a.w);
  r.h[4] = __float2bfloat16(b.x); r.h[5] = __float2bfloat16(b.y);
  r.h[6] = __float2bfloat16(b.z); r.h[7] = __float2bfloat16(b.w);
  ((uint4*)out)[i] = r.u;
}

// WT[l][col][k] = bf16(W[l][k][col]) — MFMA B-frag wants contiguous k per col
__global__ __launch_bounds__(256) void wt_kernel(const float* __restrict__ W,
                                                 __hip_bfloat16* __restrict__ WT) {
  int l = blockIdx.x;
  const float* Wl = W + (size_t)l * EMB * EMB;
  __hip_bfloat16* WTl = WT + (size_t)l * EMB * EMB;
  for (int i = threadIdx.x; i < EMB * EMB; i += 256) {
    int k = i >> 7, c = i & 127;
    WTl[c * EMB + k] = __float2bfloat16(Wl[i]);
  }
}

// ---------------- per-layer compute ----------------

// one wave per node: m[v] = bf16( deg_inv[v] * sum_{u in N(v)} xb[u] )
__global__ __launch_bounds__(256) void aggregate_kernel(const __hip_bfloat16* __restrict__ xb,
                                                        const int* __restrict__ row_ptr,
                                                        const int* __restrict__ col,
                                                        const float* __restrict__ deg_inv,
                                                        __hip_bfloat16* __restrict__ mb) {
  int gw = (blockIdx.x * 256 + threadIdx.x) >> 6;
  int lane = threadIdx.x & 63;
  int v = __builtin_amdgcn_readfirstlane(gw);  // wave-uniform node id -> SGPR
  if (v >= N_NODES) return;
  int beg = row_ptr[v];
  int end = row_ptr[v + 1];
  float accx = 0.f, accy = 0.f;
  const char* base = (const char*)xb + (size_t)lane * 4;  // 2 bf16 per lane
  for (int e = beg; e < end; ++e) {
    int u = col[e];  // wave-uniform -> scalar load
    unsigned int w = *(const unsigned int*)(base + (size_t)u * (EMB * 2));
    accx += __uint_as_float(w << 16);
    accy += __uint_as_float(w & 0xFFFF0000u);
  }
  float di = deg_inv[v];
  __hip_bfloat162 o;
  o.x = __float2bfloat16(accx * di);
  o.y = __float2bfloat16(accy * di);
  *(__hip_bfloat162*)(mb + (size_t)v * EMB + lane * 2) = o;
}

__device__ __forceinline__ float gelu_exact(float v) {
  return 0.5f * v * (1.f + erff(v * 0.70710678118654752f));
}

// x[row] += gelu(m[row] @ W + bias)   via bf16 MFMA, fp32 accum.
// 3125 blocks x 32 rows (exact). 4 waves: wave w -> rows (w>>1)*16, cols (w&1)*64.
// B-frags (W^T) held in registers: 4 coltiles x 4 ksteps x bf16x8. No LDS.
__global__ __launch_bounds__(256) void gemm_kernel(const __hip_bfloat16* __restrict__ mb,
                                                   const __hip_bfloat16* __restrict__ WTl,
                                                   const float* __restrict__ bias,
                                                   float* __restrict__ x,
                                                   __hip_bfloat16* __restrict__ xb,
                                                   int write_xb) {
  const int lane = threadIdx.x & 63;
  const int wave = threadIdx.x >> 6;
  const int rh = wave >> 1;        // row half
  const int ch = wave & 1;         // col half
  const int row0 = blockIdx.x * 32 + rh * 16;
  const int l15 = lane & 15;
  const int lhi = lane >> 4;       // 0..3

  // load B fragments: lane holds WT[col][kb..kb+8), col = ch*64+ct*16+l15
  bf16x8 bf[4][4];
#pragma unroll
  for (int ct = 0; ct < 4; ++ct) {
    const __hip_bfloat16* wp = WTl + (size_t)(ch * 64 + ct * 16 + l15) * EMB + lhi * 8;
#pragma unroll
    for (int ks = 0; ks < 4; ++ks)
      bf[ct][ks] = *(const bf16x8*)(wp + ks * 32);
  }

  // A fragments: lane holds mb[row0+l15][kb..kb+8)
  const bf16x8* ap = (const bf16x8*)(mb + (size_t)(row0 + l15) * EMB + lhi * 8);

  f32x4 acc[4];
#pragma unroll
  for (int ct = 0; ct < 4; ++ct) acc[ct] = (f32x4)(0.f);

#pragma unroll
  for (int ks = 0; ks < 4; ++ks) {
    bf16x8 af = ap[ks * 4];  // +32 bf16 per kstep
#pragma unroll
    for (int ct = 0; ct < 4; ++ct)
      acc[ct] = __builtin_amdgcn_mfma_f32_16x16x32_bf16(af, bf[ct][ks], acc[ct], 0, 0, 0);
  }

  // epilogue: C[row][col], row = row0 + lhi*4 + j, col = ch*64 + ct*16 + l15
#pragma unroll
  for (int ct = 0; ct < 4; ++ct) {
    const int colg = ch * 64 + ct * 16 + l15;
    const float bb = bias[colg];
#pragma unroll
    for (int j = 0; j < 4; ++j) {
      const int row = row0 + lhi * 4 + j;
      const size_t off = (size_t)row * EMB + colg;
      float xv = x[off] + gelu_exact(acc[ct][j] + bb);
      x[off] = xv;
      if (write_xb) xb[off] = __float2bfloat16(xv);
    }
  }
}

// in-place LayerNorm over feature dim; one wave per row
__global__ __launch_bounds__(256) void ln_kernel(float* __restrict__ x,
                                                 const float* __restrict__ gamma,
                                                 const float* __restrict__ beta) {
  int gw = (blockIdx.x * 256 + threadIdx.x) >> 6;
  int lane = threadIdx.x & 63;
  if (gw >= N_NODES) return;
  float* xp = x + (size_t)gw * EMB + lane * 2;
  float2 v = *(const float2*)xp;
  float s = v.x + v.y;
  float sq = fmaf(v.x, v.x, v.y * v.y);
  for (int off = 1; off < 64; off <<= 1) {
    s += __shfl_xor(s, off, 64);
    sq += __shfl_xor(sq, off, 64);
  }
  float mu = s * (1.f / EMB);
  float var = sq * (1.f / EMB) - mu * mu;
  float rstd = rsqrtf(var + 1e-5f);
  float2 g = *(const float2*)(gamma + lane * 2);
  float2 be = *(const float2*)(beta + lane * 2);
  float2 o;
  o.x = (v.x - mu) * rstd * g.x + be.x;
  o.y = (v.y - mu) * rstd * g.y + be.y;
  *(float2*)xp = o;
}

// ---------------- launch ----------------

extern "C" void kernel_launch(void* const* d_in, const int* in_sizes, int n_in,
                              void* d_out, int out_size, void* d_ws, size_t ws_size,
                              hipStream_t stream) {
  const int* edge_index = (const int*)d_in[0];
  const float* deg_inv = (const float*)d_in[1];
  const float* node_emb = (const float*)d_in[2];
  const float* W = (const float*)d_in[3];
  const float* b = (const float*)d_in[4];
  const float* gamma = (const float*)d_in[5];
  const float* beta = (const float*)d_in[6];
  const int* src = edge_index;
  const int* dst = edge_index + N_EDGES;
  float* x = (float*)d_out;  // fp32 residual stream lives in d_out

  // workspace layout (offsets padded to 256B)
  char* ws = (char*)d_ws;
  auto take = [&](size_t bytes) {
    char* p = ws;
    ws += (bytes + 255) & ~(size_t)255;
    return p;
  };
  __hip_bfloat16* xb = (__hip_bfloat16*)take((size_t)N_NODES * EMB * 2);  // bf16 shadow of x
  __hip_bfloat16* mb = (__hip_bfloat16*)take((size_t)N_NODES * EMB * 2);  // bf16 aggregate
  __hip_bfloat16* WT = (__hip_bfloat16*)take((size_t)N_LAYERS * EMB * EMB * 2);
  int* counts = (int*)take(N_NODES * sizeof(int));
  int* row_ptr = (int*)take((N_NODES + 1) * sizeof(int));
  int* cursor = (int*)take(N_NODES * sizeof(int));
  int* col = (int*)take(N_EDGES * sizeof(int));
  int* partials = (int*)take(512 * sizeof(int));

  hipMemcpyAsync(x, node_emb, (size_t)N_NODES * EMB * sizeof(float),
                 hipMemcpyDeviceToDevice, stream);
  hipMemsetAsync(counts, 0, N_NODES * sizeof(int), stream);

  convert_kernel<<<N_NODES * EMB / 8 / 256, 256, 0, stream>>>(node_emb, xb);
  wt_kernel<<<N_LAYERS, 256, 0, stream>>>(W, WT);

  hist_kernel<<<(N_EDGES + 255) / 256, 256, 0, stream>>>(dst, counts);
  scan1_kernel<<<N_SCAN_BLOCKS, 256, 0, stream>>>(counts, partials);
  scan2_kernel<<<1, 512, 0, stream>>>(partials);
  scan3_kernel<<<N_SCAN_BLOCKS, 256, 0, stream>>>(counts, partials, row_ptr, cursor);
  fill_kernel<<<(N_EDGES + 255) / 256, 256, 0, stream>>>(src, dst, cursor, col);

  for (int l = 0; l < N_LAYERS; ++l) {
    aggregate_kernel<<<(N_NODES + 3) / 4, 256, 0, stream>>>(xb, row_ptr, col, deg_inv, mb);
    gemm_kernel<<<N_NODES / 32, 256, 0, stream>>>(mb, WT + (size_t)l * EMB * EMB,
                                                  b + (size_t)l * EMB, x, xb,
                                                  l < N_LAYERS - 1 ? 1 : 0);
  }
  ln_kernel<<<(N_NODES + 3) / 4, 256, 0, stream>>>(x, gamma, beta);
}

// Round 4
// 518.587 us; speedup vs baseline: 2.0595x; 1.3289x over previous
//
#include <hip/hip_runtime.h>
#include <hip/hip_bf16.h>
#include <math.h>

#define N_NODES 100000
#define EMB 128
#define N_EDGES 1600000
#define N_LAYERS 3
#define SCAN_BLK 256
#define N_SCAN_BLOCKS ((N_NODES + SCAN_BLK - 1) / SCAN_BLK)  // 391

typedef __bf16 bf16x8 __attribute__((ext_vector_type(8)));
typedef float f32x4 __attribute__((ext_vector_type(4)));

// ---------------- CSR build ----------------

__global__ __launch_bounds__(256) void hist_kernel(const int* __restrict__ dst,
                                                   int* __restrict__ counts) {
  int i = blockIdx.x * 256 + threadIdx.x;
  if (i < N_EDGES) atomicAdd(&counts[dst[i]], 1);
}

__global__ __launch_bounds__(256) void scan1_kernel(const int* __restrict__ counts,
                                                    int* __restrict__ partials) {
  __shared__ int sdata[256];
  int t = threadIdx.x;
  int idx = blockIdx.x * 256 + t;
  sdata[t] = (idx < N_NODES) ? counts[idx] : 0;
  __syncthreads();
  for (int off = 128; off > 0; off >>= 1) {
    if (t < off) sdata[t] += sdata[t + off];
    __syncthreads();
  }
  if (t == 0) partials[blockIdx.x] = sdata[0];
}

__global__ __launch_bounds__(512) void scan2_kernel(int* __restrict__ partials) {
  __shared__ int s[512];
  int t = threadIdx.x;
  int v = (t < N_SCAN_BLOCKS) ? partials[t] : 0;
  s[t] = v;
  __syncthreads();
  for (int off = 1; off < 512; off <<= 1) {
    int tmp = (t >= off) ? s[t - off] : 0;
    __syncthreads();
    s[t] += tmp;
    __syncthreads();
  }
  if (t < N_SCAN_BLOCKS) partials[t] = s[t] - v;  // exclusive prefix of block sums
}

__global__ __launch_bounds__(256) void scan3_kernel(const int* __restrict__ counts,
                                                    const int* __restrict__ partials,
                                                    int* __restrict__ row_ptr,
                                                    int* __restrict__ cursor) {
  __shared__ int s[256];
  int t = threadIdx.x;
  int b = blockIdx.x;
  int idx = b * 256 + t;
  int v = (idx < N_NODES) ? counts[idx] : 0;
  s[t] = v;
  __syncthreads();
  for (int off = 1; off < 256; off <<= 1) {
    int tmp = (t >= off) ? s[t - off] : 0;
    __syncthreads();
    s[t] += tmp;
    __syncthreads();
  }
  if (idx < N_NODES) {
    int val = s[t] - v + partials[b];
    row_ptr[idx] = val;
    cursor[idx] = val;
  }
  if (b == 0 && t == 0) row_ptr[N_NODES] = N_EDGES;
}

// Group-partitioned fill: group g = blockIdx&7 (round-robin -> same XCD,
// perf heuristic only) handles only dst in [g*12500,(g+1)*12500). Writes to
// each col region then come from one XCD -> L2 merges the ~16 writes/line.
#define FILL_GRID 2048
#define FILL_CHUNK (N_EDGES / (FILL_GRID / 8))  // 6250
__global__ __launch_bounds__(256) void fill_kernel(const int* __restrict__ src,
                                                   const int* __restrict__ dst,
                                                   int* __restrict__ cursor,
                                                   int* __restrict__ col) {
  const int g = blockIdx.x & 7;
  const int j = blockIdx.x >> 3;  // 0..255
  const int lo = g * (N_NODES / 8);
  const int hi = lo + (N_NODES / 8);
  const int e0 = j * FILL_CHUNK;
  for (int i = e0 + threadIdx.x; i < e0 + FILL_CHUNK; i += 256) {
    int d = dst[i];
    int s = src[i];
    if (d >= lo && d < hi) {
      int p = atomicAdd(&cursor[d], 1);
      col[p] = s;
    }
  }
}

// ---------------- precompute ----------------

// x = node_emb (fp32 copy), xb = bf16(node_emb); 8 elems/thread
__global__ __launch_bounds__(256) void convert_kernel(const float* __restrict__ in,
                                                      float* __restrict__ x,
                                                      __hip_bfloat16* __restrict__ xb) {
  size_t i = (size_t)blockIdx.x * 256 + threadIdx.x;  // 1.6M threads exactly
  const float4* p = (const float4*)in + i * 2;
  float4 a = p[0], b = p[1];
  float4* xo = (float4*)x + i * 2;
  xo[0] = a;
  xo[1] = b;
  union { __hip_bfloat16 h[8]; uint4 u; } r;
  r.h[0] = __float2bfloat16(a.x); r.h[1] = __float2bfloat16(a.y);
  r.h[2] = __float2bfloat16(a.z); r.h[3] = __float2bfloat16(a.w);
  r.h[4] = __float2bfloat16(b.x); r.h[5] = __float2bfloat16(b.y);
  r.h[6] = __float2bfloat16(b.z); r.h[7] = __float2bfloat16(b.w);
  ((uint4*)xb)[i] = r.u;
}

// WT[l][col][k] = bf16(W[l][k][col]) — MFMA B-frag wants contiguous k per col
__global__ __launch_bounds__(256) void wt_kernel(const float* __restrict__ W,
                                                 __hip_bfloat16* __restrict__ WT) {
  int l = blockIdx.x;
  const float* Wl = W + (size_t)l * EMB * EMB;
  __hip_bfloat16* WTl = WT + (size_t)l * EMB * EMB;
  for (int i = threadIdx.x; i < EMB * EMB; i += 256) {
    int k = i >> 7, c = i & 127;
    WTl[c * EMB + k] = __float2bfloat16(Wl[i]);
  }
}

// ---------------- per-layer compute ----------------

__device__ __forceinline__ float bf_lo(unsigned int w) { return __uint_as_float(w << 16); }
__device__ __forceinline__ float bf_hi(unsigned int w) { return __uint_as_float(w & 0xFFFF0000u); }

// one wave per node: m[v] = bf16( deg_inv[v] * sum_{u in N(v)} xb[u] )
// 4x unrolled gather: batch 4 uniform col loads -> 4 independent row loads in flight.
__global__ __launch_bounds__(256) void aggregate_kernel(const __hip_bfloat16* __restrict__ xb,
                                                        const int* __restrict__ row_ptr,
                                                        const int* __restrict__ col,
                                                        const float* __restrict__ deg_inv,
                                                        __hip_bfloat16* __restrict__ mb) {
  int gw = (blockIdx.x * 256 + threadIdx.x) >> 6;
  int lane = threadIdx.x & 63;
  int v = __builtin_amdgcn_readfirstlane(gw);  // wave-uniform node id -> SGPR
  if (v >= N_NODES) return;
  int beg = row_ptr[v];
  int end = row_ptr[v + 1];
  float accx = 0.f, accy = 0.f;
  const char* base = (const char*)xb + (size_t)lane * 4;  // 2 bf16 per lane
  int e = beg;
  for (; e + 4 <= end; e += 4) {
    int u0 = col[e], u1 = col[e + 1], u2 = col[e + 2], u3 = col[e + 3];
    unsigned int w0 = *(const unsigned int*)(base + (size_t)u0 * (EMB * 2));
    unsigned int w1 = *(const unsigned int*)(base + (size_t)u1 * (EMB * 2));
    unsigned int w2 = *(const unsigned int*)(base + (size_t)u2 * (EMB * 2));
    unsigned int w3 = *(const unsigned int*)(base + (size_t)u3 * (EMB * 2));
    accx += bf_lo(w0) + bf_lo(w1) + bf_lo(w2) + bf_lo(w3);
    accy += bf_hi(w0) + bf_hi(w1) + bf_hi(w2) + bf_hi(w3);
  }
  for (; e < end; ++e) {
    int u = col[e];
    unsigned int w = *(const unsigned int*)(base + (size_t)u * (EMB * 2));
    accx += bf_lo(w);
    accy += bf_hi(w);
  }
  float di = deg_inv[v];
  __hip_bfloat162 o;
  o.x = __float2bfloat16(accx * di);
  o.y = __float2bfloat16(accy * di);
  *(__hip_bfloat162*)(mb + (size_t)v * EMB + lane * 2) = o;
}

__device__ __forceinline__ float gelu_exact(float v) {
  return 0.5f * v * (1.f + erff(v * 0.70710678118654752f));
}

// x[row] += gelu(m[row] @ W + bias)   via bf16 MFMA, fp32 accum.
// 3125 blocks x 32 rows (exact). 4 waves: wave w -> rows (w>>1)*16, cols (w&1)*64.
// B-frags (W^T) held in registers: 4 coltiles x 4 ksteps x bf16x8. No LDS.
__global__ __launch_bounds__(256) void gemm_kernel(const __hip_bfloat16* __restrict__ mb,
                                                   const __hip_bfloat16* __restrict__ WTl,
                                                   const float* __restrict__ bias,
                                                   float* __restrict__ x,
                                                   __hip_bfloat16* __restrict__ xb,
                                                   int write_xb) {
  const int lane = threadIdx.x & 63;
  const int wave = threadIdx.x >> 6;
  const int rh = wave >> 1;        // row half
  const int ch = wave & 1;         // col half
  const int row0 = blockIdx.x * 32 + rh * 16;
  const int l15 = lane & 15;
  const int lhi = lane >> 4;       // 0..3

  // load B fragments: lane holds WT[col][kb..kb+8), col = ch*64+ct*16+l15
  bf16x8 bf[4][4];
#pragma unroll
  for (int ct = 0; ct < 4; ++ct) {
    const __hip_bfloat16* wp = WTl + (size_t)(ch * 64 + ct * 16 + l15) * EMB + lhi * 8;
#pragma unroll
    for (int ks = 0; ks < 4; ++ks)
      bf[ct][ks] = *(const bf16x8*)(wp + ks * 32);
  }

  // A fragments: lane holds mb[row0+l15][kb..kb+8)
  const bf16x8* ap = (const bf16x8*)(mb + (size_t)(row0 + l15) * EMB + lhi * 8);

  f32x4 acc[4];
#pragma unroll
  for (int ct = 0; ct < 4; ++ct) acc[ct] = (f32x4)(0.f);

#pragma unroll
  for (int ks = 0; ks < 4; ++ks) {
    bf16x8 af = ap[ks * 4];  // +32 bf16 per kstep
#pragma unroll
    for (int ct = 0; ct < 4; ++ct)
      acc[ct] = __builtin_amdgcn_mfma_f32_16x16x32_bf16(af, bf[ct][ks], acc[ct], 0, 0, 0);
  }

  // epilogue: C[row][col], row = row0 + lhi*4 + j, col = ch*64 + ct*16 + l15
#pragma unroll
  for (int ct = 0; ct < 4; ++ct) {
    const int colg = ch * 64 + ct * 16 + l15;
    const float bb = bias[colg];
#pragma unroll
    for (int j = 0; j < 4; ++j) {
      const int row = row0 + lhi * 4 + j;
      const size_t off = (size_t)row * EMB + colg;
      float xv = x[off] + gelu_exact(acc[ct][j] + bb);
      x[off] = xv;
      if (write_xb) xb[off] = __float2bfloat16(xv);
    }
  }
}

// in-place LayerNorm over feature dim; one wave per row
__global__ __launch_bounds__(256) void ln_kernel(float* __restrict__ x,
                                                 const float* __restrict__ gamma,
                                                 const float* __restrict__ beta) {
  int gw = (blockIdx.x * 256 + threadIdx.x) >> 6;
  int lane = threadIdx.x & 63;
  if (gw >= N_NODES) return;
  float* xp = x + (size_t)gw * EMB + lane * 2;
  float2 v = *(const float2*)xp;
  float s = v.x + v.y;
  float sq = fmaf(v.x, v.x, v.y * v.y);
  for (int off = 1; off < 64; off <<= 1) {
    s += __shfl_xor(s, off, 64);
    sq += __shfl_xor(sq, off, 64);
  }
  float mu = s * (1.f / EMB);
  float var = sq * (1.f / EMB) - mu * mu;
  float rstd = rsqrtf(var + 1e-5f);
  float2 g = *(const float2*)(gamma + lane * 2);
  float2 be = *(const float2*)(beta + lane * 2);
  float2 o;
  o.x = (v.x - mu) * rstd * g.x + be.x;
  o.y = (v.y - mu) * rstd * g.y + be.y;
  *(float2*)xp = o;
}

// ---------------- launch ----------------

extern "C" void kernel_launch(void* const* d_in, const int* in_sizes, int n_in,
                              void* d_out, int out_size, void* d_ws, size_t ws_size,
                              hipStream_t stream) {
  const int* edge_index = (const int*)d_in[0];
  const float* deg_inv = (const float*)d_in[1];
  const float* node_emb = (const float*)d_in[2];
  const float* W = (const float*)d_in[3];
  const float* b = (const float*)d_in[4];
  const float* gamma = (const float*)d_in[5];
  const float* beta = (const float*)d_in[6];
  const int* src = edge_index;
  const int* dst = edge_index + N_EDGES;
  float* x = (float*)d_out;  // fp32 residual stream lives in d_out

  // workspace layout (offsets padded to 256B)
  char* ws = (char*)d_ws;
  auto take = [&](size_t bytes) {
    char* p = ws;
    ws += (bytes + 255) & ~(size_t)255;
    return p;
  };
  __hip_bfloat16* xb = (__hip_bfloat16*)take((size_t)N_NODES * EMB * 2);  // bf16 shadow of x
  __hip_bfloat16* mb = (__hip_bfloat16*)take((size_t)N_NODES * EMB * 2);  // bf16 aggregate
  __hip_bfloat16* WT = (__hip_bfloat16*)take((size_t)N_LAYERS * EMB * EMB * 2);
  int* counts = (int*)take(N_NODES * sizeof(int));
  int* row_ptr = (int*)take((N_NODES + 1) * sizeof(int));
  int* cursor = (int*)take(N_NODES * sizeof(int));
  int* col = (int*)take(N_EDGES * sizeof(int));
  int* partials = (int*)take(512 * sizeof(int));

  hipMemsetAsync(counts, 0, N_NODES * sizeof(int), stream);

  convert_kernel<<<N_NODES * EMB / 8 / 256, 256, 0, stream>>>(node_emb, x, xb);
  wt_kernel<<<N_LAYERS, 256, 0, stream>>>(W, WT);

  hist_kernel<<<(N_EDGES + 255) / 256, 256, 0, stream>>>(dst, counts);
  scan1_kernel<<<N_SCAN_BLOCKS, 256, 0, stream>>>(counts, partials);
  scan2_kernel<<<1, 512, 0, stream>>>(partials);
  scan3_kernel<<<N_SCAN_BLOCKS, 256, 0, stream>>>(counts, partials, row_ptr, cursor);
  fill_kernel<<<FILL_GRID, 256, 0, stream>>>(src, dst, cursor, col);

  for (int l = 0; l < N_LAYERS; ++l) {
    aggregate_kernel<<<(N_NODES + 3) / 4, 256, 0, stream>>>(xb, row_ptr, col, deg_inv, mb);
    gemm_kernel<<<N_NODES / 32, 256, 0, stream>>>(mb, WT + (size_t)l * EMB * EMB,
                                                  b + (size_t)l * EMB, x, xb,
                                                  l < N_LAYERS - 1 ? 1 : 0);
  }
  ln_kernel<<<(N_NODES + 3) / 4, 256, 0, stream>>>(x, gamma, beta);
}